// Round 10
// baseline (263.205 us; speedup 1.0000x reference)
//
#include <hip/hip_runtime.h>
#include <stdint.h>

typedef __attribute__((ext_vector_type(8))) short short8;
typedef __attribute__((ext_vector_type(4))) float f32x4;

__device__ __forceinline__ unsigned short f2bf(float f) {
  unsigned u = __float_as_uint(f);
  u += 0x7FFF + ((u >> 16) & 1);
  return (unsigned short)(u >> 16);
}
__device__ __forceinline__ float bf2f(unsigned short h) {
  return __uint_as_float(((unsigned)h) << 16);
}

// Packed fragment layout (k-major) for mfma_f32_16x16x32_bf16 operands:
// frag tile (rt, kc): short off = (kc*NRT + rt)*512 + lane*8,
// lane = (row&15) + 16*((k&31)>>3), elem = k&7. 1 frag = wave-contiguous 1KB.

// ---------------- merged prep: pack x + low (blocks 0..787), pack weights, zero V pads ----------------
__global__ __launch_bounds__(256) void k_prep2(const float* __restrict__ x,
                                               const float* __restrict__ lora_a,
                                               const float* __restrict__ qkv_w,
                                               const float* __restrict__ out_w,
                                               unsigned short* __restrict__ Apk,
                                               float* __restrict__ low,
                                               unsigned short* __restrict__ Wq,
                                               unsigned short* __restrict__ Wo,
                                               unsigned short* __restrict__ vt) {
  __shared__ unsigned short xs[16 * 776];
  __shared__ float As[8 * 768];
  const int bid = blockIdx.x;
  const int t = threadIdx.x;
  if (bid < 788) {
    const int mt = bid;
    const float4* x4 = (const float4*)(x + (size_t)mt * 16 * 768);
#pragma unroll
    for (int i = 0; i < 12; ++i) {
      float4 v = x4[i * 256 + t];
      int e0 = (i * 256 + t) * 4;
      int row = e0 / 768, col = e0 - row * 768;
      unsigned short* d = &xs[row * 776 + col];
      d[0] = f2bf(v.x); d[1] = f2bf(v.y); d[2] = f2bf(v.z); d[3] = f2bf(v.w);
    }
    for (int i = t; i < 1536; i += 256) ((float4*)As)[i] = ((const float4*)lora_a)[i];
    __syncthreads();
    const int w = t >> 6, l = t & 63;
    float acc[4][8];
#pragma unroll
    for (int r = 0; r < 4; ++r)
#pragma unroll
      for (int k = 0; k < 8; ++k) acc[r][k] = 0.f;
    for (int j = 0; j < 12; ++j) {
      int d = j * 64 + l;
#pragma unroll
      for (int r = 0; r < 4; ++r) {
        float xv = bf2f(xs[(w * 4 + r) * 776 + d]);
#pragma unroll
        for (int k = 0; k < 8; ++k) acc[r][k] += xv * As[k * 768 + d];
      }
    }
#pragma unroll
    for (int r = 0; r < 4; ++r)
#pragma unroll
      for (int k = 0; k < 8; ++k) {
        float a = acc[r][k];
        for (int dd = 1; dd < 64; dd <<= 1) a += __shfl_xor(a, dd);
        if (l == 0) low[((size_t)mt * 16 + w * 4 + r) * 8 + k] = 2.0f * a;
      }
    const int lr = l & 15, lg = l >> 4;
#pragma unroll
    for (int kk = 0; kk < 6; ++kk) {
      int kc = w * 6 + kk;
      short8 v = *(const short8*)(&xs[lr * 776 + kc * 32 + lg * 8]);
      *(short8*)(Apk + (size_t)(kc * 788 + mt) * 512 + l * 8) = v;
    }
  } else if (bid < 1940) {
    const bool isq = bid < 1652;
    const float* W = isq ? qkv_w : out_w;
    unsigned short* dst = isq ? Wq : Wo;
    const int NRT = isq ? 144 : 48;
    const int base = isq ? 788 : 1652;
    int wv = ((bid - base) * 256 + t) >> 6;
    int l = t & 63;
    int rt = wv / 24, kc = wv - rt * 24;
    int lr = l & 15, lg = l >> 4;
    const float* src = W + (size_t)(rt * 16 + lr) * 768 + kc * 32 + lg * 8;
    float4 a = *(const float4*)src;
    float4 b = *(const float4*)(src + 4);
    short8 o;
    o[0] = f2bf(a.x); o[1] = f2bf(a.y); o[2] = f2bf(a.z); o[3] = f2bf(a.w);
    o[4] = f2bf(b.x); o[5] = f2bf(b.y); o[6] = f2bf(b.z); o[7] = f2bf(b.w);
    *(short8*)(dst + (size_t)(kc * NRT + rt) * 512 + l * 8) = o;
  } else {
    int r = (bid - 1940) * 256 + t;  // [0, 49152)
    unsigned short* d = vt + (size_t)r * 224 + 197;
#pragma unroll
    for (int c = 0; c < 27; ++c) d[c] = 0;
  }
}

// ---------------- rank-8 LoRA low from PACKED (k-major) bf16 input ----------------
__global__ __launch_bounds__(256) void k_low_pk(const unsigned short* __restrict__ Apk,
                                                const float* __restrict__ lora_a,
                                                float* __restrict__ low, int M) {
  __shared__ float As[8 * 768];
  for (int i = threadIdx.x; i < 1536; i += 256) ((float4*)As)[i] = ((const float4*)lora_a)[i];
  __syncthreads();
  int w = threadIdx.x >> 6, l = threadIdx.x & 63;
  int m = blockIdx.x * 4 + w;
  if (m >= M) return;
  const int mt = m >> 4, mr = m & 15;
  const int kcb = l >> 5, lgp = (l & 31) >> 3, e = l & 7;
  float acc[8] = {0, 0, 0, 0, 0, 0, 0, 0};
  for (int j = 0; j < 12; ++j) {
    int d = j * 64 + l;
    float xv = bf2f(Apk[((size_t)((j * 2 + kcb) * 788 + mt) * 64 + mr + 16 * lgp) * 8 + e]);
#pragma unroll
    for (int r = 0; r < 8; ++r) acc[r] += xv * As[r * 768 + d];
  }
#pragma unroll
  for (int r = 0; r < 8; ++r) {
    for (int dd = 1; dd < 64; dd <<= 1) acc[r] += __shfl_xor(acc[r], dd);
    if (l == 0) low[(size_t)m * 8 + r] = 2.0f * acc[r];
  }
}

// ---------------- wide packed-fragment GEMM: 1 wave = 128x64 tile, no LDS/barriers ----------------
// 43.7 FLOP per L1-byte (vs 32 at 64x64) -> L1-BW floor ~= MFMA floor.
// Block = 4 waves = 128x256. Grid = 99 * (NT_TOT/4). MODE 0 qkv scatter, MODE 1 f32 out.
template <int MODE, int NT4, int NRTB>
__global__ __launch_bounds__(256) void k_gw(
    const unsigned short* __restrict__ Apk, const unsigned short* __restrict__ Bpk,
    const float* __restrict__ bias, const float* __restrict__ low,
    const float* __restrict__ lorab, unsigned short* __restrict__ Qg,
    unsigned short* __restrict__ Kg, unsigned short* __restrict__ Vtg,
    float* __restrict__ outp, int M) {
  const int w = threadIdx.x >> 6, l = threadIdx.x & 63;
  const int lr = l & 15, lg = l >> 4;
  const int nwg = gridDim.x;
  const int orig = blockIdx.x;
  const int qq = nwg >> 3, rr = nwg & 7, xcd = orig & 7;
  const int wgid = (xcd < rr ? xcd * (qq + 1) : rr * (qq + 1) + (xcd - rr) * qq) + (orig >> 3);
  const int mg = wgid / NT4, ng = wgid - mg * NT4;  // ng fastest: A-panel L2 reuse
  const int nt = ng * 4 + w;
  const int m0 = mg * 128, n0 = nt * 64;

  const size_t KSA = 788 * 512;   // shorts per kc plane (A)
  const size_t KSB = NRTB * 512;  // shorts per kc plane (B)
  const unsigned short* pa = Apk + (size_t)(mg * 8) * 512 + l * 8;
  const unsigned short* pb = Bpk + (size_t)(nt * 4) * 512 + l * 8;

  f32x4 acc[8][4];
#pragma unroll
  for (int i = 0; i < 8; ++i)
#pragma unroll
    for (int j = 0; j < 4; ++j) acc[i][j] = (f32x4){0.f, 0.f, 0.f, 0.f};

  short8 af[2][8], bf[2][4];
#define LDA8(dst, kt) \
  { const unsigned short* q_ = pa + (size_t)(kt) * KSA; \
    _Pragma("unroll") for (int i_ = 0; i_ < 8; ++i_) dst[i_] = *(const short8*)(q_ + i_ * 512); }
#define LDB4(dst, kt) \
  { const unsigned short* q_ = pb + (size_t)(kt) * KSB; \
    _Pragma("unroll") for (int i_ = 0; i_ < 4; ++i_) dst[i_] = *(const short8*)(q_ + i_ * 512); }
#define MFMA32(afr, bfr) \
  _Pragma("unroll") for (int mf = 0; mf < 8; ++mf) \
  _Pragma("unroll") for (int nf = 0; nf < 4; ++nf) \
    acc[mf][nf] = __builtin_amdgcn_mfma_f32_16x16x32_bf16(afr[mf], bfr[nf], acc[mf][nf], 0, 0, 0);

  LDB4(bf[0], 0);
  LDA8(af[0], 0);
#pragma unroll
  for (int kt = 0; kt < 24; ++kt) {
    const int cur = kt & 1, nxt = cur ^ 1;
    if (kt + 1 < 24) {
      LDB4(bf[nxt], kt + 1);
      LDA8(af[nxt], kt + 1);
    }
    __builtin_amdgcn_s_setprio(1);
    MFMA32(af[cur], bf[cur]);
    __builtin_amdgcn_s_setprio(0);
  }
#undef LDA8
#undef LDB4
#undef MFMA32

  // epilogue: bias + rank-8 LoRA
  float bo[4];
  float4 lb0[4], lb1[4];
#pragma unroll
  for (int nf = 0; nf < 4; ++nf) {
    int o = n0 + nf * 16 + lr;
    bo[nf] = bias[o];
    const float4* lb4 = (const float4*)(lorab + (size_t)o * 8);
    lb0[nf] = lb4[0];
    lb1[nf] = lb4[1];
  }
  const int which = nt / 12;
  const int hh = nt - which * 12;
#pragma unroll
  for (int mf = 0; mf < 8; ++mf) {
#pragma unroll
    for (int v = 0; v < 4; ++v) {
      int m = m0 + mf * 16 + lg * 4 + v;
      if (m < M) {
        const float4* lp4 = (const float4*)(low + (size_t)m * 8);
        float4 l0 = lp4[0], l1 = lp4[1];
        int b = m / 197;
        int n = m - b * 197;
#pragma unroll
        for (int nf = 0; nf < 4; ++nf) {
          float val = acc[mf][nf][v] + bo[nf];
          val += l0.x * lb0[nf].x + l0.y * lb0[nf].y + l0.z * lb0[nf].z + l0.w * lb0[nf].w;
          val += l1.x * lb1[nf].x + l1.y * lb1[nf].y + l1.z * lb1[nf].z + l1.w * lb1[nf].w;
          if (MODE == 0) {
            int hd = nf * 16 + lr;
            int bh = b * 12 + hh;
            unsigned short hv = f2bf(val);
            if (which == 0)      Qg[(bh * 224 + n) * 64 + hd] = hv;
            else if (which == 1) Kg[(bh * 224 + n) * 64 + hd] = hv;
            else                 Vtg[(bh * 64 + hd) * 224 + n] = hv;
          } else {
            outp[(size_t)m * 768 + n0 + nf * 16 + lr] = val;
          }
        }
      }
    }
  }
}

// ---------------- attention: one block per (b,h); writes PACKED (k-major) aout ----------------
__global__ __launch_bounds__(256) void k_attn(const unsigned short* __restrict__ Qg,
                                              const unsigned short* __restrict__ Kg,
                                              const unsigned short* __restrict__ Vtg,
                                              unsigned short* __restrict__ Apk) {
  __shared__ __align__(16) unsigned short Ps[4][16 * 224];
  const int bh = blockIdx.x;
  const int b = bh / 12, h = bh - b * 12;
  const unsigned short* Qb = Qg + (size_t)bh * (224 * 64);
  const unsigned short* Kb = Kg + (size_t)bh * (224 * 64);
  const unsigned short* Vb = Vtg + (size_t)bh * (64 * 224);
  const int w = threadIdx.x >> 6, l = threadIdx.x & 63;
  const int lr = l & 15, lg = l >> 4;
  for (int t = w; t < 13; t += 4) {
    const int q0 = t * 16;
    short8 aq0 = *(const short8*)(Qb + (q0 + lr) * 64 + lg * 8);
    short8 aq1 = *(const short8*)(Qb + (q0 + lr) * 64 + 32 + lg * 8);
    f32x4 s[14];
#pragma unroll
    for (int jt = 0; jt < 14; ++jt) {
      f32x4 a = (f32x4){0.f, 0.f, 0.f, 0.f};
      short8 bk0 = *(const short8*)(Kb + (jt * 16 + lr) * 64 + lg * 8);
      short8 bk1 = *(const short8*)(Kb + (jt * 16 + lr) * 64 + 32 + lg * 8);
      a = __builtin_amdgcn_mfma_f32_16x16x32_bf16(aq0, bk0, a, 0, 0, 0);
      a = __builtin_amdgcn_mfma_f32_16x16x32_bf16(aq1, bk1, a, 0, 0, 0);
      s[jt] = a;
    }
    float mx[4] = {-3.0e38f, -3.0e38f, -3.0e38f, -3.0e38f};
#pragma unroll
    for (int jt = 0; jt < 14; ++jt) {
      bool valid = (jt * 16 + lr) < 197;
#pragma unroll
      for (int v = 0; v < 4; ++v) {
        float sv = valid ? s[jt][v] : -1.0e30f;
        s[jt][v] = sv;
        mx[v] = fmaxf(mx[v], sv);
      }
    }
#pragma unroll
    for (int v = 0; v < 4; ++v) {
      mx[v] = fmaxf(mx[v], __shfl_xor(mx[v], 1));
      mx[v] = fmaxf(mx[v], __shfl_xor(mx[v], 2));
      mx[v] = fmaxf(mx[v], __shfl_xor(mx[v], 4));
      mx[v] = fmaxf(mx[v], __shfl_xor(mx[v], 8));
    }
    float sum[4] = {0.f, 0.f, 0.f, 0.f};
    const float cc = 0.125f * 1.44269504088896341f;
#pragma unroll
    for (int jt = 0; jt < 14; ++jt)
#pragma unroll
      for (int v = 0; v < 4; ++v) {
        float pv = exp2f((s[jt][v] - mx[v]) * cc);
        s[jt][v] = pv;
        sum[v] += pv;
      }
#pragma unroll
    for (int v = 0; v < 4; ++v) {
      sum[v] += __shfl_xor(sum[v], 1);
      sum[v] += __shfl_xor(sum[v], 2);
      sum[v] += __shfl_xor(sum[v], 4);
      sum[v] += __shfl_xor(sum[v], 8);
    }
    float inv[4];
#pragma unroll
    for (int v = 0; v < 4; ++v) inv[v] = 1.0f / sum[v];
    unsigned short* pw = &Ps[w][0];
#pragma unroll
    for (int jt = 0; jt < 14; ++jt)
#pragma unroll
      for (int v = 0; v < 4; ++v)
        pw[(lg * 4 + v) * 224 + jt * 16 + lr] = f2bf(s[jt][v] * inv[v]);
    f32x4 oacc[4];
#pragma unroll
    for (int jo = 0; jo < 4; ++jo) oacc[jo] = (f32x4){0.f, 0.f, 0.f, 0.f};
#pragma unroll
    for (int kk = 0; kk < 7; ++kk) {
      short8 pa = *(const short8*)(pw + lr * 224 + kk * 32 + lg * 8);
#pragma unroll
      for (int jo = 0; jo < 4; ++jo) {
        short8 bv = *(const short8*)(Vb + (jo * 16 + lr) * 224 + kk * 32 + lg * 8);
        oacc[jo] = __builtin_amdgcn_mfma_f32_16x16x32_bf16(pa, bv, oacc[jo], 0, 0, 0);
      }
    }
#pragma unroll
    for (int jo = 0; jo < 4; ++jo) {
      const int kc = h * 2 + (jo >> 1);
      const int lgp = (jo & 1) * 2 + (lr >> 3);
      const int e = lr & 7;
#pragma unroll
      for (int v = 0; v < 4; ++v) {
        int n = q0 + lg * 4 + v;
        if (n < 197) {
          int m = b * 197 + n;
          Apk[((size_t)(kc * 788 + (m >> 4)) * 64 + (m & 15) + 16 * lgp) * 8 + e] = f2bf(oacc[jo][v]);
        }
      }
    }
  }
}

extern "C" void kernel_launch(void* const* d_in, const int* in_sizes, int n_in,
                              void* d_out, int out_size, void* d_ws, size_t ws_size,
                              hipStream_t stream) {
  const float* x      = (const float*)d_in[0];
  const float* qkv_w  = (const float*)d_in[1];
  const float* qkv_b  = (const float*)d_in[2];
  const float* qkv_la = (const float*)d_in[3];
  const float* qkv_lb = (const float*)d_in[4];
  const float* out_w  = (const float*)d_in[5];
  const float* out_b  = (const float*)d_in[6];
  const float* out_la = (const float*)d_in[7];
  const float* out_lb = (const float*)d_in[8];
  float* out = (float*)d_out;

  const int M = 64 * 197;  // 12608 = 788*16 = 197*64
  char* p = (char*)d_ws;
  auto carve = [&](size_t bytes) {
    char* r = p;
    p += (bytes + 255) & ~(size_t)255;
    return r;
  };
  // +32KB pad: mg=98 fragment reads touch rt 788..791 (past 788) — keep in-bounds
  unsigned short* Apk  = (unsigned short*)carve((size_t)788 * 24 * 512 * 2 + 32768);
  unsigned short* Wqpk = (unsigned short*)carve((size_t)144 * 24 * 512 * 2);
  unsigned short* Wopk = (unsigned short*)carve((size_t)48 * 24 * 512 * 2);
  float* lowq          = (float*)carve((size_t)M * 8 * 4);
  float* lowo          = (float*)carve((size_t)M * 8 * 4);
  unsigned short* Qg   = (unsigned short*)carve((size_t)768 * 224 * 64 * 2);
  unsigned short* Kg   = (unsigned short*)carve((size_t)768 * 224 * 64 * 2);
  unsigned short* Vtg  = (unsigned short*)carve((size_t)768 * 64 * 224 * 2);

  // merged prep: 788 (pack x + low) + 864 (pack qkv_w) + 288 (pack out_w) + 192 (V pads)
  k_prep2<<<2132, 256, 0, stream>>>(x, qkv_la, qkv_w, out_w, Apk, lowq, Wqpk, Wopk, Vtg);
  // qkv: 99 mg x 9 block-n-groups = 891 blocks (block = 128x256)
  k_gw<0, 9, 144><<<891, 256, 0, stream>>>(Apk, Wqpk, qkv_b, lowq, qkv_lb, Qg, Kg, Vtg, nullptr, M);
  k_attn<<<768, 256, 0, stream>>>(Qg, Kg, Vtg, Apk);  // Apk now holds packed attn-out
  k_low_pk<<<(M + 3) / 4, 256, 0, stream>>>(Apk, out_la, lowo, M);
  // out: 99 mg x 3 = 297 blocks
  k_gw<1, 3, 48><<<297, 256, 0, stream>>>(Apk, Wopk, out_b, lowo, out_lb, nullptr, nullptr, nullptr, out, M);
}

// Round 11
// 202.902 us; speedup vs baseline: 1.2972x; 1.2972x over previous
//
#include <hip/hip_runtime.h>
#include <stdint.h>

typedef __attribute__((ext_vector_type(8))) short short8;
typedef __attribute__((ext_vector_type(4))) float f32x4;

__device__ __forceinline__ unsigned short f2bf(float f) {
  unsigned u = __float_as_uint(f);
  u += 0x7FFF + ((u >> 16) & 1);
  return (unsigned short)(u >> 16);
}
__device__ __forceinline__ float bf2f(unsigned short h) {
  return __uint_as_float(((unsigned)h) << 16);
}

// Packed fragment layout (k-major) for mfma_f32_16x16x32_bf16 operands:
// frag tile (rt, kc): short off = (kc*NRT + rt)*512 + lane*8,
// lane = (row&15) + 16*((k&31)>>3), elem = k&7. 1 frag = wave-contiguous 1KB.

// ---------------- merged prep ----------------
// blocks [0,788): pack x f32 -> packed bf16
// blocks [788,1940): pack weights with LoRA fold: W' = W + 2*lb@la
// blocks [1940,2132): zero V seq-pad rows
__global__ __launch_bounds__(256) void k_prep3(const float* __restrict__ x,
                                               const float* __restrict__ qkv_w,
                                               const float* __restrict__ out_w,
                                               const float* __restrict__ qkv_la,
                                               const float* __restrict__ qkv_lb,
                                               const float* __restrict__ out_la,
                                               const float* __restrict__ out_lb,
                                               unsigned short* __restrict__ Apk,
                                               unsigned short* __restrict__ Wq,
                                               unsigned short* __restrict__ Wo,
                                               unsigned short* __restrict__ vt) {
  __shared__ unsigned short xs[16 * 776];
  const int bid = blockIdx.x;
  const int t = threadIdx.x;
  if (bid < 788) {
    const int mt = bid;
    const float4* x4 = (const float4*)(x + (size_t)mt * 16 * 768);
#pragma unroll
    for (int i = 0; i < 12; ++i) {
      float4 v = x4[i * 256 + t];
      int e0 = (i * 256 + t) * 4;
      int row = e0 / 768, col = e0 - row * 768;
      unsigned short* d = &xs[row * 776 + col];
      d[0] = f2bf(v.x); d[1] = f2bf(v.y); d[2] = f2bf(v.z); d[3] = f2bf(v.w);
    }
    __syncthreads();
    const int w = t >> 6, l = t & 63;
    const int lr = l & 15, lg = l >> 4;
#pragma unroll
    for (int kk = 0; kk < 6; ++kk) {
      int kc = w * 6 + kk;
      short8 v = *(const short8*)(&xs[lr * 776 + kc * 32 + lg * 8]);
      *(short8*)(Apk + (size_t)(kc * 788 + mt) * 512 + l * 8) = v;
    }
  } else if (bid < 1940) {
    const bool isq = bid < 1652;
    const float* W = isq ? qkv_w : out_w;
    const float* la = isq ? qkv_la : out_la;
    const float* lb = isq ? qkv_lb : out_lb;
    unsigned short* dst = isq ? Wq : Wo;
    const int NRT = isq ? 144 : 48;
    const int base = isq ? 788 : 1652;
    int wv = ((bid - base) * 256 + t) >> 6;
    int l = t & 63;
    int rt = wv / 24, kc = wv - rt * 24;
    int lr = l & 15, lg = l >> 4;
    const int o = rt * 16 + lr;
    const int d0 = kc * 32 + lg * 8;
    const float* src = W + (size_t)o * 768 + d0;
    float4 a = *(const float4*)src;
    float4 b = *(const float4*)(src + 4);
    float wvv[8] = {a.x, a.y, a.z, a.w, b.x, b.y, b.z, b.w};
    const float4* lb4 = (const float4*)(lb + (size_t)o * 8);
    float4 p0 = lb4[0], p1 = lb4[1];
    float lbv[8] = {p0.x, p0.y, p0.z, p0.w, p1.x, p1.y, p1.z, p1.w};
#pragma unroll
    for (int r = 0; r < 8; ++r) {
      const float4* la4 = (const float4*)(la + (size_t)r * 768 + d0);
      float4 c = la4[0], dd = la4[1];
      float s = 2.0f * lbv[r];
      wvv[0] += s * c.x;  wvv[1] += s * c.y;  wvv[2] += s * c.z;  wvv[3] += s * c.w;
      wvv[4] += s * dd.x; wvv[5] += s * dd.y; wvv[6] += s * dd.z; wvv[7] += s * dd.w;
    }
    short8 oo;
#pragma unroll
    for (int e = 0; e < 8; ++e) oo[e] = f2bf(wvv[e]);
    *(short8*)(dst + (size_t)(kc * NRT + rt) * 512 + l * 8) = oo;
  } else {
    int r = (bid - 1940) * 256 + t;  // [0, 49152)
    unsigned short* d = vt + (size_t)r * 224 + 197;
#pragma unroll
    for (int c = 0; c < 27; ++c) d[c] = 0;
  }
}

// ---------------- packed-fragment GEMM, shared-B blocks (R8 winner, lean epilogue) ----------------
// Block = 4 waves: same n-strip (B frags L1-shared), 4 adjacent m-strips.
// MODE 0: qkv (NT=36, NRTB=144) scatter to Q/K/Vt + bias. MODE 1: out (NT=12, NRTB=48) f32 + bias.
template <int MODE, int NT, int NRTB>
__global__ __launch_bounds__(256, 3) void k_gp3(
    const unsigned short* __restrict__ Apk, const unsigned short* __restrict__ Bpk,
    const float* __restrict__ bias, unsigned short* __restrict__ Qg,
    unsigned short* __restrict__ Kg, unsigned short* __restrict__ Vtg,
    float* __restrict__ outp) {
  const int w = threadIdx.x >> 6, l = threadIdx.x & 63;
  const int lr = l & 15, lg = l >> 4;
  const int nwg = gridDim.x;
  const int orig = blockIdx.x;
  const int qq = nwg >> 3, rr = nwg & 7, xcd = orig & 7;
  const int wgid = (xcd < rr ? xcd * (qq + 1) : rr * (qq + 1) + (xcd - rr) * qq) + (orig >> 3);
  const int mg = wgid / NT, nt = wgid - mg * NT;  // nt fastest: A-panel L2-hot
  int mtw = mg * 4 + w;
  if (mtw > 196) mtw = 196;  // duplicate waves write identical data (benign)
  const int m0 = mtw * 64, n0 = nt * 64;

  const size_t KSA = 788 * 512;   // shorts per kc plane (A)
  const size_t KSB = NRTB * 512;  // shorts per kc plane (B)
  const unsigned short* pa = Apk + (size_t)(mtw * 4) * 512 + l * 8;
  const unsigned short* pb = Bpk + (size_t)(nt * 4) * 512 + l * 8;

  f32x4 acc[4][4];
#pragma unroll
  for (int i = 0; i < 4; ++i)
#pragma unroll
    for (int j = 0; j < 4; ++j) acc[i][j] = (f32x4){0.f, 0.f, 0.f, 0.f};

  short8 ab[2][4], bb[2][4];
#define LDA4(dst, kt) \
  { const unsigned short* q_ = pa + (size_t)(kt) * KSA; \
    dst[0] = *(const short8*)(q_); dst[1] = *(const short8*)(q_ + 512); \
    dst[2] = *(const short8*)(q_ + 1024); dst[3] = *(const short8*)(q_ + 1536); }
#define LDB4(dst, kt) \
  { const unsigned short* q_ = pb + (size_t)(kt) * KSB; \
    dst[0] = *(const short8*)(q_); dst[1] = *(const short8*)(q_ + 512); \
    dst[2] = *(const short8*)(q_ + 1024); dst[3] = *(const short8*)(q_ + 1536); }
#define MFMA16(af, bf) \
  _Pragma("unroll") for (int mf = 0; mf < 4; ++mf) \
  _Pragma("unroll") for (int nf = 0; nf < 4; ++nf) \
    acc[mf][nf] = __builtin_amdgcn_mfma_f32_16x16x32_bf16(af[mf], bf[nf], acc[mf][nf], 0, 0, 0);

  LDB4(bb[0], 0);
  LDA4(ab[0], 0);
#pragma unroll
  for (int kt = 0; kt < 24; ++kt) {
    const int cur = kt & 1, nxt = cur ^ 1;
    if (kt + 1 < 24) {
      LDB4(bb[nxt], kt + 1);
      LDA4(ab[nxt], kt + 1);
    }
    __builtin_amdgcn_s_setprio(1);
    MFMA16(ab[cur], bb[cur]);
    __builtin_amdgcn_s_setprio(0);
  }
#undef LDA4
#undef LDB4
#undef MFMA16

  // epilogue: bias only (LoRA folded into weights)
  float bo[4];
#pragma unroll
  for (int nf = 0; nf < 4; ++nf) bo[nf] = bias[n0 + nf * 16 + lr];
  const int which = nt / 12;
  const int hh = nt - which * 12;
#pragma unroll
  for (int mf = 0; mf < 4; ++mf) {
#pragma unroll
    for (int v = 0; v < 4; ++v) {
      int m = m0 + mf * 16 + lg * 4 + v;
      int b = m / 197;
      int n = m - b * 197;
#pragma unroll
      for (int nf = 0; nf < 4; ++nf) {
        float val = acc[mf][nf][v] + bo[nf];
        if (MODE == 0) {
          int hd = nf * 16 + lr;
          int bh = b * 12 + hh;
          unsigned short hv = f2bf(val);
          if (which == 0)      Qg[(bh * 224 + n) * 64 + hd] = hv;
          else if (which == 1) Kg[(bh * 224 + n) * 64 + hd] = hv;
          else                 Vtg[(bh * 64 + hd) * 224 + n] = hv;
        } else {
          outp[(size_t)m * 768 + n0 + nf * 16 + lr] = val;
        }
      }
    }
  }
}

// ---------------- attention: 512 thr (8 waves) per (b,h); writes PACKED (k-major) aout ----------------
__global__ __launch_bounds__(512) void k_attn8(const unsigned short* __restrict__ Qg,
                                               const unsigned short* __restrict__ Kg,
                                               const unsigned short* __restrict__ Vtg,
                                               unsigned short* __restrict__ Apk) {
  __shared__ __align__(16) unsigned short Ps[8][16 * 224];
  const int bh = blockIdx.x;
  const int b = bh / 12, h = bh - b * 12;
  const unsigned short* Qb = Qg + (size_t)bh * (224 * 64);
  const unsigned short* Kb = Kg + (size_t)bh * (224 * 64);
  const unsigned short* Vb = Vtg + (size_t)bh * (64 * 224);
  const int w = threadIdx.x >> 6, l = threadIdx.x & 63;
  const int lr = l & 15, lg = l >> 4;
  for (int t = w; t < 13; t += 8) {
    const int q0 = t * 16;
    short8 aq0 = *(const short8*)(Qb + (q0 + lr) * 64 + lg * 8);
    short8 aq1 = *(const short8*)(Qb + (q0 + lr) * 64 + 32 + lg * 8);
    f32x4 s[14];
#pragma unroll
    for (int jt = 0; jt < 14; ++jt) {
      f32x4 a = (f32x4){0.f, 0.f, 0.f, 0.f};
      short8 bk0 = *(const short8*)(Kb + (jt * 16 + lr) * 64 + lg * 8);
      short8 bk1 = *(const short8*)(Kb + (jt * 16 + lr) * 64 + 32 + lg * 8);
      a = __builtin_amdgcn_mfma_f32_16x16x32_bf16(aq0, bk0, a, 0, 0, 0);
      a = __builtin_amdgcn_mfma_f32_16x16x32_bf16(aq1, bk1, a, 0, 0, 0);
      s[jt] = a;
    }
    float mx[4] = {-3.0e38f, -3.0e38f, -3.0e38f, -3.0e38f};
#pragma unroll
    for (int jt = 0; jt < 14; ++jt) {
      bool valid = (jt * 16 + lr) < 197;
#pragma unroll
      for (int v = 0; v < 4; ++v) {
        float sv = valid ? s[jt][v] : -1.0e30f;
        s[jt][v] = sv;
        mx[v] = fmaxf(mx[v], sv);
      }
    }
#pragma unroll
    for (int v = 0; v < 4; ++v) {
      mx[v] = fmaxf(mx[v], __shfl_xor(mx[v], 1));
      mx[v] = fmaxf(mx[v], __shfl_xor(mx[v], 2));
      mx[v] = fmaxf(mx[v], __shfl_xor(mx[v], 4));
      mx[v] = fmaxf(mx[v], __shfl_xor(mx[v], 8));
    }
    float sum[4] = {0.f, 0.f, 0.f, 0.f};
    const float cc = 0.125f * 1.44269504088896341f;
#pragma unroll
    for (int jt = 0; jt < 14; ++jt)
#pragma unroll
      for (int v = 0; v < 4; ++v) {
        float pv = exp2f((s[jt][v] - mx[v]) * cc);
        s[jt][v] = pv;
        sum[v] += pv;
      }
#pragma unroll
    for (int v = 0; v < 4; ++v) {
      sum[v] += __shfl_xor(sum[v], 1);
      sum[v] += __shfl_xor(sum[v], 2);
      sum[v] += __shfl_xor(sum[v], 4);
      sum[v] += __shfl_xor(sum[v], 8);
    }
    float inv[4];
#pragma unroll
    for (int v = 0; v < 4; ++v) inv[v] = 1.0f / sum[v];
    unsigned short* pw = &Ps[w][0];
#pragma unroll
    for (int jt = 0; jt < 14; ++jt)
#pragma unroll
      for (int v = 0; v < 4; ++v)
        pw[(lg * 4 + v) * 224 + jt * 16 + lr] = f2bf(s[jt][v] * inv[v]);
    f32x4 oacc[4];
#pragma unroll
    for (int jo = 0; jo < 4; ++jo) oacc[jo] = (f32x4){0.f, 0.f, 0.f, 0.f};
#pragma unroll
    for (int kk = 0; kk < 7; ++kk) {
      short8 pa = *(const short8*)(pw + lr * 224 + kk * 32 + lg * 8);
#pragma unroll
      for (int jo = 0; jo < 4; ++jo) {
        short8 bv = *(const short8*)(Vb + (jo * 16 + lr) * 224 + kk * 32 + lg * 8);
        oacc[jo] = __builtin_amdgcn_mfma_f32_16x16x32_bf16(pa, bv, oacc[jo], 0, 0, 0);
      }
    }
#pragma unroll
    for (int jo = 0; jo < 4; ++jo) {
      const int kc = h * 2 + (jo >> 1);
      const int lgp = (jo & 1) * 2 + (lr >> 3);
      const int e = lr & 7;
#pragma unroll
      for (int v = 0; v < 4; ++v) {
        int n = q0 + lg * 4 + v;
        if (n < 197) {
          int m = b * 197 + n;
          Apk[((size_t)(kc * 788 + (m >> 4)) * 64 + (m & 15) + 16 * lgp) * 8 + e] = f2bf(oacc[jo][v]);
        }
      }
    }
  }
}

extern "C" void kernel_launch(void* const* d_in, const int* in_sizes, int n_in,
                              void* d_out, int out_size, void* d_ws, size_t ws_size,
                              hipStream_t stream) {
  const float* x      = (const float*)d_in[0];
  const float* qkv_w  = (const float*)d_in[1];
  const float* qkv_b  = (const float*)d_in[2];
  const float* qkv_la = (const float*)d_in[3];
  const float* qkv_lb = (const float*)d_in[4];
  const float* out_w  = (const float*)d_in[5];
  const float* out_b  = (const float*)d_in[6];
  const float* out_la = (const float*)d_in[7];
  const float* out_lb = (const float*)d_in[8];
  float* out = (float*)d_out;

  char* p = (char*)d_ws;
  auto carve = [&](size_t bytes) {
    char* r = p;
    p += (bytes + 255) & ~(size_t)255;
    return r;
  };
  // +32KB pad: edge m-group fragment reads may touch past rt=788 — keep in-bounds
  unsigned short* Apk  = (unsigned short*)carve((size_t)788 * 24 * 512 * 2 + 32768);
  unsigned short* Wqpk = (unsigned short*)carve((size_t)144 * 24 * 512 * 2);
  unsigned short* Wopk = (unsigned short*)carve((size_t)48 * 24 * 512 * 2);
  unsigned short* Qg   = (unsigned short*)carve((size_t)768 * 224 * 64 * 2);
  unsigned short* Kg   = (unsigned short*)carve((size_t)768 * 224 * 64 * 2);
  unsigned short* Vtg  = (unsigned short*)carve((size_t)768 * 64 * 224 * 2);

  // prep: 788 (pack x) + 864 (pack qkv_w + LoRA fold) + 288 (pack out_w + fold) + 192 (V pads)
  k_prep3<<<2132, 256, 0, stream>>>(x, qkv_w, out_w, qkv_la, qkv_lb, out_la, out_lb,
                                    Apk, Wqpk, Wopk, Vtg);
  // qkv: 50 mg x 36 nt (block = 256x64)
  k_gp3<0, 36, 144><<<50 * 36, 256, 0, stream>>>(Apk, Wqpk, qkv_b, Qg, Kg, Vtg, nullptr);
  k_attn8<<<768, 512, 0, stream>>>(Qg, Kg, Vtg, Apk);  // Apk now holds packed attn-out
  // out: 50 mg x 12 nt
  k_gp3<1, 12, 48><<<50 * 12, 256, 0, stream>>>(Apk, Wopk, out_b, nullptr, nullptr, nullptr, out);
}

// Round 12
// 196.586 us; speedup vs baseline: 1.3389x; 1.0321x over previous
//
#include <hip/hip_runtime.h>
#include <stdint.h>

typedef __attribute__((ext_vector_type(8))) short short8;
typedef __attribute__((ext_vector_type(4))) float f32x4;

#define SB __builtin_amdgcn_sched_barrier(0)

__device__ __forceinline__ unsigned short f2bf(float f) {
  unsigned u = __float_as_uint(f);
  u += 0x7FFF + ((u >> 16) & 1);
  return (unsigned short)(u >> 16);
}
__device__ __forceinline__ float bf2f(unsigned short h) {
  return __uint_as_float(((unsigned)h) << 16);
}

// Packed fragment layout (k-major) for mfma_f32_16x16x32_bf16 operands:
// frag tile (rt, kc): short off = (kc*NRT + rt)*512 + lane*8,
// lane = (row&15) + 16*((k&31)>>3), elem = k&7. 1 frag = wave-contiguous 1KB.

// ---------------- merged prep ----------------
__global__ __launch_bounds__(256) void k_prep3(const float* __restrict__ x,
                                               const float* __restrict__ qkv_w,
                                               const float* __restrict__ out_w,
                                               const float* __restrict__ qkv_la,
                                               const float* __restrict__ qkv_lb,
                                               const float* __restrict__ out_la,
                                               const float* __restrict__ out_lb,
                                               unsigned short* __restrict__ Apk,
                                               unsigned short* __restrict__ Wq,
                                               unsigned short* __restrict__ Wo,
                                               unsigned short* __restrict__ vt) {
  __shared__ unsigned short xs[16 * 776];
  const int bid = blockIdx.x;
  const int t = threadIdx.x;
  if (bid < 788) {
    const int mt = bid;
    const float4* x4 = (const float4*)(x + (size_t)mt * 16 * 768);
#pragma unroll
    for (int i = 0; i < 12; ++i) {
      float4 v = x4[i * 256 + t];
      int e0 = (i * 256 + t) * 4;
      int row = e0 / 768, col = e0 - row * 768;
      unsigned short* d = &xs[row * 776 + col];
      d[0] = f2bf(v.x); d[1] = f2bf(v.y); d[2] = f2bf(v.z); d[3] = f2bf(v.w);
    }
    __syncthreads();
    const int w = t >> 6, l = t & 63;
    const int lr = l & 15, lg = l >> 4;
#pragma unroll
    for (int kk = 0; kk < 6; ++kk) {
      int kc = w * 6 + kk;
      short8 v = *(const short8*)(&xs[lr * 776 + kc * 32 + lg * 8]);
      *(short8*)(Apk + (size_t)(kc * 788 + mt) * 512 + l * 8) = v;
    }
  } else if (bid < 1940) {
    const bool isq = bid < 1652;
    const float* W = isq ? qkv_w : out_w;
    const float* la = isq ? qkv_la : out_la;
    const float* lb = isq ? qkv_lb : out_lb;
    unsigned short* dst = isq ? Wq : Wo;
    const int NRT = isq ? 144 : 48;
    const int base = isq ? 788 : 1652;
    int wv = ((bid - base) * 256 + t) >> 6;
    int l = t & 63;
    int rt = wv / 24, kc = wv - rt * 24;
    int lr = l & 15, lg = l >> 4;
    const int o = rt * 16 + lr;
    const int d0 = kc * 32 + lg * 8;
    const float* src = W + (size_t)o * 768 + d0;
    float4 a = *(const float4*)src;
    float4 b = *(const float4*)(src + 4);
    float wvv[8] = {a.x, a.y, a.z, a.w, b.x, b.y, b.z, b.w};
    const float4* lb4 = (const float4*)(lb + (size_t)o * 8);
    float4 p0 = lb4[0], p1 = lb4[1];
    float lbv[8] = {p0.x, p0.y, p0.z, p0.w, p1.x, p1.y, p1.z, p1.w};
#pragma unroll
    for (int r = 0; r < 8; ++r) {
      const float4* la4 = (const float4*)(la + (size_t)r * 768 + d0);
      float4 c = la4[0], dd = la4[1];
      float s = 2.0f * lbv[r];
      wvv[0] += s * c.x;  wvv[1] += s * c.y;  wvv[2] += s * c.z;  wvv[3] += s * c.w;
      wvv[4] += s * dd.x; wvv[5] += s * dd.y; wvv[6] += s * dd.z; wvv[7] += s * dd.w;
    }
    short8 oo;
#pragma unroll
    for (int e = 0; e < 8; ++e) oo[e] = f2bf(wvv[e]);
    *(short8*)(dst + (size_t)(kc * NRT + rt) * 512 + l * 8) = oo;
  } else {
    int r = (bid - 1940) * 256 + t;  // [0, 49152)
    unsigned short* d = vt + (size_t)r * 224 + 197;
#pragma unroll
    for (int c = 0; c < 27; ++c) d[c] = 0;
  }
}

// ---------------- GEMM: B via LDS (separate port), A reg depth-2, shared-B 4-wave block ----------------
// Block = 4 waves: same n-strip, 4 adjacent m-strips. B strip (96KB) staged in two
// 48KB halves via global_load_lds; one refill barrier pair at kt=11/12.
// MODE 0: qkv (NT=36, NRTB=144) scatter + bias. MODE 1: out (NT=12, NRTB=48) f32 + bias.
template <int MODE, int NT, int NRTB>
__global__ __launch_bounds__(256, 3) void k_gp4(
    const unsigned short* __restrict__ Apk, const unsigned short* __restrict__ Bpk,
    const float* __restrict__ bias, unsigned short* __restrict__ Qg,
    unsigned short* __restrict__ Kg, unsigned short* __restrict__ Vtg,
    float* __restrict__ outp) {
  __shared__ __align__(16) char bl[49152];  // 12 kc-slots x 4 rt x 1KB
  const int w = threadIdx.x >> 6, l = threadIdx.x & 63;
  const int lr = l & 15, lg = l >> 4;
  const int nwg = gridDim.x;
  const int orig = blockIdx.x;
  const int qq = nwg >> 3, rr = nwg & 7, xcd = orig & 7;
  const int wgid = (xcd < rr ? xcd * (qq + 1) : rr * (qq + 1) + (xcd - rr) * qq) + (orig >> 3);
  const int mg = wgid / NT, nt = wgid - mg * NT;  // nt fastest: A-panel L2-hot
  int mtw = mg * 4 + w;
  if (mtw > 196) mtw = 196;  // duplicate waves write identical data (benign)
  const int m0 = mtw * 64, n0 = nt * 64;

  const size_t KSA = 788 * 512;  // shorts per kc plane (A)
  const unsigned short* pa = Apk + (size_t)(mtw * 4) * 512 + l * 8;

  auto* lds3 = (__attribute__((address_space(3))) char*)bl;
  // wave w stages rt=w of its block's n-strip, one chunk per kc
  auto STB = [&](int kc) {
    const unsigned short* g = Bpk + ((size_t)kc * NRTB + nt * 4 + w) * 512 + l * 8;
    __builtin_amdgcn_global_load_lds((const __attribute__((address_space(1))) void*)g,
                                     (__attribute__((address_space(3))) void*)(lds3 + ((kc % 12) * 4 + w) * 1024),
                                     16, 0, 0);
  };

  f32x4 acc[4][4];
#pragma unroll
  for (int i = 0; i < 4; ++i)
#pragma unroll
    for (int j = 0; j < 4; ++j) acc[i][j] = (f32x4){0.f, 0.f, 0.f, 0.f};

  short8 ab[2][4];
#define LDA4(dst, kt) \
  { const unsigned short* q_ = pa + (size_t)(kt) * KSA; \
    dst[0] = *(const short8*)(q_); dst[1] = *(const short8*)(q_ + 512); \
    dst[2] = *(const short8*)(q_ + 1024); dst[3] = *(const short8*)(q_ + 1536); }

  // prologue: stage B half 1 (kc 0..11), drain, barrier; then A kt0/kt1
#pragma unroll
  for (int kc = 0; kc < 12; ++kc) STB(kc);
  asm volatile("s_waitcnt vmcnt(0)" ::: "memory");
  SB;
  __builtin_amdgcn_s_barrier();
  LDA4(ab[0], 0);
  LDA4(ab[1], 1);

#pragma unroll
  for (int kt = 0; kt < 24; ++kt) {
    if (kt == 12) {
      // own refills certified (leaves only the 4 A(kt=13) loads), then sync all waves
      asm volatile("s_waitcnt vmcnt(4)" ::: "memory");
      SB;
      __builtin_amdgcn_s_barrier();
    }
    short8 bfr[4];
    const char* sbase = (const char*)bl + (kt % 12) * 4096;
#pragma unroll
    for (int nf = 0; nf < 4; ++nf)
      bfr[nf] = *(const short8*)(sbase + nf * 1024 + l * 16);
    if (kt == 11) {
      // all waves' B reads of half 1 complete before refill overwrites
      asm volatile("s_waitcnt lgkmcnt(0)" ::: "memory");
      SB;
      __builtin_amdgcn_s_barrier();
#pragma unroll
      for (int kc = 12; kc < 24; ++kc) STB(kc);
    }
    __builtin_amdgcn_s_setprio(1);
#pragma unroll
    for (int mf = 0; mf < 4; ++mf)
#pragma unroll
      for (int nf = 0; nf < 4; ++nf)
        acc[mf][nf] = __builtin_amdgcn_mfma_f32_16x16x32_bf16(ab[kt & 1][mf], bfr[nf], acc[mf][nf], 0, 0, 0);
    __builtin_amdgcn_s_setprio(0);
    if (kt + 2 < 24) LDA4(ab[kt & 1], kt + 2);  // overwrite just-consumed buffer
  }
#undef LDA4

  // epilogue: bias only (LoRA folded into weights)
  float bo[4];
#pragma unroll
  for (int nf = 0; nf < 4; ++nf) bo[nf] = bias[n0 + nf * 16 + lr];
  const int which = nt / 12;
  const int hh = nt - which * 12;
#pragma unroll
  for (int mf = 0; mf < 4; ++mf) {
#pragma unroll
    for (int v = 0; v < 4; ++v) {
      int m = m0 + mf * 16 + lg * 4 + v;
      int b = m / 197;
      int n = m - b * 197;
#pragma unroll
      for (int nf = 0; nf < 4; ++nf) {
        float val = acc[mf][nf][v] + bo[nf];
        if (MODE == 0) {
          int hd = nf * 16 + lr;
          int bh = b * 12 + hh;
          unsigned short hv = f2bf(val);
          if (which == 0)      Qg[(bh * 224 + n) * 64 + hd] = hv;
          else if (which == 1) Kg[(bh * 224 + n) * 64 + hd] = hv;
          else                 Vtg[(bh * 64 + hd) * 224 + n] = hv;
        } else {
          outp[(size_t)m * 768 + n0 + nf * 16 + lr] = val;
        }
      }
    }
  }
}

// ---------------- attention: 512 thr (8 waves) per (b,h); writes PACKED (k-major) aout ----------------
__global__ __launch_bounds__(512) void k_attn8(const unsigned short* __restrict__ Qg,
                                               const unsigned short* __restrict__ Kg,
                                               const unsigned short* __restrict__ Vtg,
                                               unsigned short* __restrict__ Apk) {
  __shared__ __align__(16) unsigned short Ps[8][16 * 224];
  const int bh = blockIdx.x;
  const int b = bh / 12, h = bh - b * 12;
  const unsigned short* Qb = Qg + (size_t)bh * (224 * 64);
  const unsigned short* Kb = Kg + (size_t)bh * (224 * 64);
  const unsigned short* Vb = Vtg + (size_t)bh * (64 * 224);
  const int w = threadIdx.x >> 6, l = threadIdx.x & 63;
  const int lr = l & 15, lg = l >> 4;
  for (int t = w; t < 13; t += 8) {
    const int q0 = t * 16;
    short8 aq0 = *(const short8*)(Qb + (q0 + lr) * 64 + lg * 8);
    short8 aq1 = *(const short8*)(Qb + (q0 + lr) * 64 + 32 + lg * 8);
    f32x4 s[14];
#pragma unroll
    for (int jt = 0; jt < 14; ++jt) {
      f32x4 a = (f32x4){0.f, 0.f, 0.f, 0.f};
      short8 bk0 = *(const short8*)(Kb + (jt * 16 + lr) * 64 + lg * 8);
      short8 bk1 = *(const short8*)(Kb + (jt * 16 + lr) * 64 + 32 + lg * 8);
      a = __builtin_amdgcn_mfma_f32_16x16x32_bf16(aq0, bk0, a, 0, 0, 0);
      a = __builtin_amdgcn_mfma_f32_16x16x32_bf16(aq1, bk1, a, 0, 0, 0);
      s[jt] = a;
    }
    float mx[4] = {-3.0e38f, -3.0e38f, -3.0e38f, -3.0e38f};
#pragma unroll
    for (int jt = 0; jt < 14; ++jt) {
      bool valid = (jt * 16 + lr) < 197;
#pragma unroll
      for (int v = 0; v < 4; ++v) {
        float sv = valid ? s[jt][v] : -1.0e30f;
        s[jt][v] = sv;
        mx[v] = fmaxf(mx[v], sv);
      }
    }
#pragma unroll
    for (int v = 0; v < 4; ++v) {
      mx[v] = fmaxf(mx[v], __shfl_xor(mx[v], 1));
      mx[v] = fmaxf(mx[v], __shfl_xor(mx[v], 2));
      mx[v] = fmaxf(mx[v], __shfl_xor(mx[v], 4));
      mx[v] = fmaxf(mx[v], __shfl_xor(mx[v], 8));
    }
    float sum[4] = {0.f, 0.f, 0.f, 0.f};
    const float cc = 0.125f * 1.44269504088896341f;
#pragma unroll
    for (int jt = 0; jt < 14; ++jt)
#pragma unroll
      for (int v = 0; v < 4; ++v) {
        float pv = exp2f((s[jt][v] - mx[v]) * cc);
        s[jt][v] = pv;
        sum[v] += pv;
      }
#pragma unroll
    for (int v = 0; v < 4; ++v) {
      sum[v] += __shfl_xor(sum[v], 1);
      sum[v] += __shfl_xor(sum[v], 2);
      sum[v] += __shfl_xor(sum[v], 4);
      sum[v] += __shfl_xor(sum[v], 8);
    }
    float inv[4];
#pragma unroll
    for (int v = 0; v < 4; ++v) inv[v] = 1.0f / sum[v];
    unsigned short* pw = &Ps[w][0];
#pragma unroll
    for (int jt = 0; jt < 14; ++jt)
#pragma unroll
      for (int v = 0; v < 4; ++v)
        pw[(lg * 4 + v) * 224 + jt * 16 + lr] = f2bf(s[jt][v] * inv[v]);
    f32x4 oacc[4];
#pragma unroll
    for (int jo = 0; jo < 4; ++jo) oacc[jo] = (f32x4){0.f, 0.f, 0.f, 0.f};
#pragma unroll
    for (int kk = 0; kk < 7; ++kk) {
      short8 pa = *(const short8*)(pw + lr * 224 + kk * 32 + lg * 8);
#pragma unroll
      for (int jo = 0; jo < 4; ++jo) {
        short8 bv = *(const short8*)(Vb + (jo * 16 + lr) * 224 + kk * 32 + lg * 8);
        oacc[jo] = __builtin_amdgcn_mfma_f32_16x16x32_bf16(pa, bv, oacc[jo], 0, 0, 0);
      }
    }
#pragma unroll
    for (int jo = 0; jo < 4; ++jo) {
      const int kc = h * 2 + (jo >> 1);
      const int lgp = (jo & 1) * 2 + (lr >> 3);
      const int e = lr & 7;
#pragma unroll
      for (int v = 0; v < 4; ++v) {
        int n = q0 + lg * 4 + v;
        if (n < 197) {
          int m = b * 197 + n;
          Apk[((size_t)(kc * 788 + (m >> 4)) * 64 + (m & 15) + 16 * lgp) * 8 + e] = f2bf(oacc[jo][v]);
        }
      }
    }
  }
}

extern "C" void kernel_launch(void* const* d_in, const int* in_sizes, int n_in,
                              void* d_out, int out_size, void* d_ws, size_t ws_size,
                              hipStream_t stream) {
  const float* x      = (const float*)d_in[0];
  const float* qkv_w  = (const float*)d_in[1];
  const float* qkv_b  = (const float*)d_in[2];
  const float* qkv_la = (const float*)d_in[3];
  const float* qkv_lb = (const float*)d_in[4];
  const float* out_w  = (const float*)d_in[5];
  const float* out_b  = (const float*)d_in[6];
  const float* out_la = (const float*)d_in[7];
  const float* out_lb = (const float*)d_in[8];
  float* out = (float*)d_out;

  char* p = (char*)d_ws;
  auto carve = [&](size_t bytes) {
    char* r = p;
    p += (bytes + 255) & ~(size_t)255;
    return r;
  };
  unsigned short* Apk  = (unsigned short*)carve((size_t)788 * 24 * 512 * 2 + 32768);
  unsigned short* Wqpk = (unsigned short*)carve((size_t)144 * 24 * 512 * 2);
  unsigned short* Wopk = (unsigned short*)carve((size_t)48 * 24 * 512 * 2);
  unsigned short* Qg   = (unsigned short*)carve((size_t)768 * 224 * 64 * 2);
  unsigned short* Kg   = (unsigned short*)carve((size_t)768 * 224 * 64 * 2);
  unsigned short* Vtg  = (unsigned short*)carve((size_t)768 * 64 * 224 * 2);

  // prep: 788 (pack x) + 864 (pack qkv_w + fold) + 288 (pack out_w + fold) + 192 (V pads)
  k_prep3<<<2132, 256, 0, stream>>>(x, qkv_w, out_w, qkv_la, qkv_lb, out_la, out_lb,
                                    Apk, Wqpk, Wopk, Vtg);
  // qkv: 50 mg x 36 nt (block = 256x64)
  k_gp4<0, 36, 144><<<50 * 36, 256, 0, stream>>>(Apk, Wqpk, qkv_b, Qg, Kg, Vtg, nullptr);
  k_attn8<<<768, 512, 0, stream>>>(Qg, Kg, Vtg, Apk);  // Apk now holds packed attn-out
  // out: 50 mg x 12 nt
  k_gp4<1, 12, 48><<<50 * 12, 256, 0, stream>>>(Apk, Wopk, out_b, nullptr, nullptr, nullptr, out);
}

// Round 13
// 174.014 us; speedup vs baseline: 1.5126x; 1.1297x over previous
//
#include <hip/hip_runtime.h>
#include <stdint.h>

typedef __attribute__((ext_vector_type(8))) short short8;
typedef __attribute__((ext_vector_type(4))) float f32x4;

#define SB __builtin_amdgcn_sched_barrier(0)

__device__ __forceinline__ unsigned short f2bf(float f) {
  unsigned u = __float_as_uint(f);
  u += 0x7FFF + ((u >> 16) & 1);
  return (unsigned short)(u >> 16);
}

// Packed fragment layout (k-major) for mfma_f32_16x16x32_bf16 operands:
// frag tile (rt, kc): short off = (kc*NRT + rt)*512 + L*8 + e,
// L = (row&15) + 16*((k&31)>>3), e = k&7. 1 frag = wave-contiguous 1KB.
// Per-head planes (28KB = 14336 shorts): Q/K: 14 rt (n) x 2 kc (d);
// Vt: 4 rt (d) x 7 kc (n), tile index kc*4+rt.

// ---------------- merged prep ----------------
__global__ __launch_bounds__(256) void k_prep3(const float* __restrict__ x,
                                               const float* __restrict__ qkv_w,
                                               const float* __restrict__ out_w,
                                               const float* __restrict__ qkv_la,
                                               const float* __restrict__ qkv_lb,
                                               const float* __restrict__ out_la,
                                               const float* __restrict__ out_lb,
                                               unsigned short* __restrict__ Apk,
                                               unsigned short* __restrict__ Wq,
                                               unsigned short* __restrict__ Wo,
                                               unsigned short* __restrict__ Vtpk) {
  __shared__ unsigned short xs[16 * 776];
  const int bid = blockIdx.x;
  const int t = threadIdx.x;
  if (bid < 788) {
    const int mt = bid;
    const float4* x4 = (const float4*)(x + (size_t)mt * 16 * 768);
#pragma unroll
    for (int i = 0; i < 12; ++i) {
      float4 v = x4[i * 256 + t];
      int e0 = (i * 256 + t) * 4;
      int row = e0 / 768, col = e0 - row * 768;
      unsigned short* d = &xs[row * 776 + col];
      d[0] = f2bf(v.x); d[1] = f2bf(v.y); d[2] = f2bf(v.z); d[3] = f2bf(v.w);
    }
    __syncthreads();
    const int w = t >> 6, l = t & 63;
    const int lr = l & 15, lg = l >> 4;
#pragma unroll
    for (int kk = 0; kk < 6; ++kk) {
      int kc = w * 6 + kk;
      short8 v = *(const short8*)(&xs[lr * 776 + kc * 32 + lg * 8]);
      *(short8*)(Apk + (size_t)(kc * 788 + mt) * 512 + l * 8) = v;
    }
  } else if (bid < 1940) {
    const bool isq = bid < 1652;
    const float* W = isq ? qkv_w : out_w;
    const float* la = isq ? qkv_la : out_la;
    const float* lb = isq ? qkv_lb : out_lb;
    unsigned short* dst = isq ? Wq : Wo;
    const int NRT = isq ? 144 : 48;
    const int base = isq ? 788 : 1652;
    int wv = ((bid - base) * 256 + t) >> 6;
    int l = t & 63;
    int rt = wv / 24, kc = wv - rt * 24;
    int lr = l & 15, lg = l >> 4;
    const int o = rt * 16 + lr;
    const int d0 = kc * 32 + lg * 8;
    const float* src = W + (size_t)o * 768 + d0;
    float4 a = *(const float4*)src;
    float4 b = *(const float4*)(src + 4);
    float wvv[8] = {a.x, a.y, a.z, a.w, b.x, b.y, b.z, b.w};
    const float4* lb4 = (const float4*)(lb + (size_t)o * 8);
    float4 p0 = lb4[0], p1 = lb4[1];
    float lbv[8] = {p0.x, p0.y, p0.z, p0.w, p1.x, p1.y, p1.z, p1.w};
#pragma unroll
    for (int r = 0; r < 8; ++r) {
      const float4* la4 = (const float4*)(la + (size_t)r * 768 + d0);
      float4 c = la4[0], dd = la4[1];
      float s = 2.0f * lbv[r];
      wvv[0] += s * c.x;  wvv[1] += s * c.y;  wvv[2] += s * c.z;  wvv[3] += s * c.w;
      wvv[4] += s * dd.x; wvv[5] += s * dd.y; wvv[6] += s * dd.z; wvv[7] += s * dd.w;
    }
    short8 oo;
#pragma unroll
    for (int e = 0; e < 8; ++e) oo[e] = f2bf(wvv[e]);
    *(short8*)(dst + (size_t)(kc * NRT + rt) * 512 + l * 8) = oo;
  } else {
    // zero V seq-pad in PACKED Vt layout: thread r = bh*64+hd, n in [197,224)
    int r = (bid - 1940) * 256 + t;  // [0, 49152)
    int bh = r >> 6, hd = r & 63;
    unsigned short* base = Vtpk + (size_t)bh * 14336 + (24 + (hd >> 4)) * 512;  // kc=6 plane
#pragma unroll
    for (int c = 0; c < 27; ++c) {
      int n = 197 + c;
      base[((hd & 15) + 16 * ((n & 31) >> 3)) * 8 + (n & 7)] = 0;
    }
  }
}

// ---------------- GEMM: B via LDS, A reg depth-2, shared-B 4-wave block ----------------
// MODE 0: qkv (NT=36, NRTB=144) scatter to PACKED Q/K/Vt + bias. MODE 1: out (NT=12, NRTB=48).
template <int MODE, int NT, int NRTB>
__global__ __launch_bounds__(256, 3) void k_gp4(
    const unsigned short* __restrict__ Apk, const unsigned short* __restrict__ Bpk,
    const float* __restrict__ bias, unsigned short* __restrict__ Qpk,
    unsigned short* __restrict__ Kpk, unsigned short* __restrict__ Vtpk,
    float* __restrict__ outp) {
  __shared__ __align__(16) char bl[49152];  // 12 kc-slots x 4 rt x 1KB
  const int w = threadIdx.x >> 6, l = threadIdx.x & 63;
  const int lr = l & 15, lg = l >> 4;
  const int nwg = gridDim.x;
  const int orig = blockIdx.x;
  const int qq = nwg >> 3, rr = nwg & 7, xcd = orig & 7;
  const int wgid = (xcd < rr ? xcd * (qq + 1) : rr * (qq + 1) + (xcd - rr) * qq) + (orig >> 3);
  const int mg = wgid / NT, nt = wgid - mg * NT;
  int mtw = mg * 4 + w;
  if (mtw > 196) mtw = 196;
  const int m0 = mtw * 64, n0 = nt * 64;

  const size_t KSA = 788 * 512;
  const unsigned short* pa = Apk + (size_t)(mtw * 4) * 512 + l * 8;

  auto* lds3 = (__attribute__((address_space(3))) char*)bl;
  auto STB = [&](int kc) {
    const unsigned short* g = Bpk + ((size_t)kc * NRTB + nt * 4 + w) * 512 + l * 8;
    __builtin_amdgcn_global_load_lds((const __attribute__((address_space(1))) void*)g,
                                     (__attribute__((address_space(3))) void*)(lds3 + ((kc % 12) * 4 + w) * 1024),
                                     16, 0, 0);
  };

  f32x4 acc[4][4];
#pragma unroll
  for (int i = 0; i < 4; ++i)
#pragma unroll
    for (int j = 0; j < 4; ++j) acc[i][j] = (f32x4){0.f, 0.f, 0.f, 0.f};

  short8 ab[2][4];
#define LDA4(dst, kt) \
  { const unsigned short* q_ = pa + (size_t)(kt) * KSA; \
    dst[0] = *(const short8*)(q_); dst[1] = *(const short8*)(q_ + 512); \
    dst[2] = *(const short8*)(q_ + 1024); dst[3] = *(const short8*)(q_ + 1536); }

#pragma unroll
  for (int kc = 0; kc < 12; ++kc) STB(kc);
  asm volatile("s_waitcnt vmcnt(0)" ::: "memory");
  SB;
  __builtin_amdgcn_s_barrier();
  LDA4(ab[0], 0);
  LDA4(ab[1], 1);

#pragma unroll
  for (int kt = 0; kt < 24; ++kt) {
    if (kt == 12) {
      asm volatile("s_waitcnt vmcnt(4)" ::: "memory");
      SB;
      __builtin_amdgcn_s_barrier();
    }
    short8 bfr[4];
    const char* sbase = (const char*)bl + (kt % 12) * 4096;
#pragma unroll
    for (int nf = 0; nf < 4; ++nf)
      bfr[nf] = *(const short8*)(sbase + nf * 1024 + l * 16);
    if (kt == 11) {
      asm volatile("s_waitcnt lgkmcnt(0)" ::: "memory");
      SB;
      __builtin_amdgcn_s_barrier();
#pragma unroll
      for (int kc = 12; kc < 24; ++kc) STB(kc);
    }
    __builtin_amdgcn_s_setprio(1);
#pragma unroll
    for (int mf = 0; mf < 4; ++mf)
#pragma unroll
      for (int nf = 0; nf < 4; ++nf)
        acc[mf][nf] = __builtin_amdgcn_mfma_f32_16x16x32_bf16(ab[kt & 1][mf], bfr[nf], acc[mf][nf], 0, 0, 0);
    __builtin_amdgcn_s_setprio(0);
    if (kt + 2 < 24) LDA4(ab[kt & 1], kt + 2);
  }
#undef LDA4

  // epilogue: bias; MODE 0 scatter into PACKED per-head fragment planes
  float bo[4];
#pragma unroll
  for (int nf = 0; nf < 4; ++nf) bo[nf] = bias[n0 + nf * 16 + lr];
  const int which = nt / 12;
  const int hh = nt - which * 12;
#pragma unroll
  for (int mf = 0; mf < 4; ++mf) {
#pragma unroll
    for (int v = 0; v < 4; ++v) {
      int m = m0 + mf * 16 + lg * 4 + v;
      int b = m / 197;
      int n = m - b * 197;
#pragma unroll
      for (int nf = 0; nf < 4; ++nf) {
        float val = acc[mf][nf][v] + bo[nf];
        if (MODE == 0) {
          int bh = b * 12 + hh;
          unsigned short hv = f2bf(val);
          if (which == 2) {
            // Vt: rt = hd>>4 = nf, kc = n>>5, L = lr + 16*((n&31)>>3), e = n&7
            Vtpk[(size_t)bh * 14336 + ((n >> 5) * 4 + nf) * 512 +
                 (lr + 16 * ((n & 31) >> 3)) * 8 + (n & 7)] = hv;
          } else {
            // Q/K: rt = n>>4, kc = nf>>1, L = (n&15) + 16*((nf&1)*2 + (lr>>3)), e = lr&7
            unsigned short* dst = (which == 0) ? Qpk : Kpk;
            dst[(size_t)bh * 14336 + ((nf >> 1) * 14 + (n >> 4)) * 512 +
                ((n & 15) + 16 * ((nf & 1) * 2 + (lr >> 3))) * 8 + (lr & 7)] = hv;
          }
        } else {
          outp[(size_t)m * 768 + n0 + nf * 16 + lr] = val;
        }
      }
    }
  }
}

// ---------------- attention: packed-fragment operands, 8 waves per (b,h) ----------------
__global__ __launch_bounds__(512) void k_attn8p(const unsigned short* __restrict__ Qpk,
                                                const unsigned short* __restrict__ Kpk,
                                                const unsigned short* __restrict__ Vtpk,
                                                unsigned short* __restrict__ Apk) {
  __shared__ __align__(16) unsigned short Ps[8][7 * 512];
  const int bh = blockIdx.x;
  const int b = bh / 12, h = bh - b * 12;
  const unsigned short* Qb = Qpk + (size_t)bh * 14336;
  const unsigned short* Kb = Kpk + (size_t)bh * 14336;
  const unsigned short* Vb = Vtpk + (size_t)bh * 14336;
  const int w = threadIdx.x >> 6, l = threadIdx.x & 63;
  const int lr = l & 15, lg = l >> 4;
  for (int t = w; t < 13; t += 8) {
    short8 aq0 = *(const short8*)(Qb + (size_t)t * 512 + l * 8);
    short8 aq1 = *(const short8*)(Qb + (size_t)(14 + t) * 512 + l * 8);
    f32x4 s[14];
#pragma unroll
    for (int jt = 0; jt < 14; ++jt) {
      f32x4 a = (f32x4){0.f, 0.f, 0.f, 0.f};
      short8 bk0 = *(const short8*)(Kb + (size_t)jt * 512 + l * 8);
      short8 bk1 = *(const short8*)(Kb + (size_t)(14 + jt) * 512 + l * 8);
      a = __builtin_amdgcn_mfma_f32_16x16x32_bf16(aq0, bk0, a, 0, 0, 0);
      a = __builtin_amdgcn_mfma_f32_16x16x32_bf16(aq1, bk1, a, 0, 0, 0);
      s[jt] = a;
    }
    float mx[4] = {-3.0e38f, -3.0e38f, -3.0e38f, -3.0e38f};
#pragma unroll
    for (int jt = 0; jt < 14; ++jt) {
      bool valid = (jt * 16 + lr) < 197;
#pragma unroll
      for (int v = 0; v < 4; ++v) {
        float sv = valid ? s[jt][v] : -1.0e30f;
        s[jt][v] = sv;
        mx[v] = fmaxf(mx[v], sv);
      }
    }
#pragma unroll
    for (int v = 0; v < 4; ++v) {
      mx[v] = fmaxf(mx[v], __shfl_xor(mx[v], 1));
      mx[v] = fmaxf(mx[v], __shfl_xor(mx[v], 2));
      mx[v] = fmaxf(mx[v], __shfl_xor(mx[v], 4));
      mx[v] = fmaxf(mx[v], __shfl_xor(mx[v], 8));
    }
    float sum[4] = {0.f, 0.f, 0.f, 0.f};
    const float cc = 0.125f * 1.44269504088896341f;
#pragma unroll
    for (int jt = 0; jt < 14; ++jt)
#pragma unroll
      for (int v = 0; v < 4; ++v) {
        float pv = exp2f((s[jt][v] - mx[v]) * cc);
        s[jt][v] = pv;
        sum[v] += pv;
      }
#pragma unroll
    for (int v = 0; v < 4; ++v) {
      sum[v] += __shfl_xor(sum[v], 1);
      sum[v] += __shfl_xor(sum[v], 2);
      sum[v] += __shfl_xor(sum[v], 4);
      sum[v] += __shfl_xor(sum[v], 8);
    }
    float inv[4];
#pragma unroll
    for (int v = 0; v < 4; ++v) inv[v] = 1.0f / sum[v];
    // write P to LDS in fragment-major layout (read side = contiguous b128)
    unsigned short* pw = &Ps[w][0];
#pragma unroll
    for (int jt = 0; jt < 14; ++jt) {
      const int base = (jt >> 1) * 512 + ((jt & 1) * 2 + (lr >> 3)) * 128 + (lr & 7);
#pragma unroll
      for (int v = 0; v < 4; ++v)
        pw[base + (lg * 4 + v) * 8] = f2bf(s[jt][v] * inv[v]);
    }
    f32x4 oacc[4];
#pragma unroll
    for (int jo = 0; jo < 4; ++jo) oacc[jo] = (f32x4){0.f, 0.f, 0.f, 0.f};
#pragma unroll
    for (int kk = 0; kk < 7; ++kk) {
      short8 pa = *(const short8*)(pw + kk * 512 + l * 8);
#pragma unroll
      for (int jo = 0; jo < 4; ++jo) {
        short8 bv = *(const short8*)(Vb + (size_t)(kk * 4 + jo) * 512 + l * 8);
        oacc[jo] = __builtin_amdgcn_mfma_f32_16x16x32_bf16(pa, bv, oacc[jo], 0, 0, 0);
      }
    }
    // write PACKED k-major aout for the out-GEMM
    const int q0 = t * 16;
#pragma unroll
    for (int jo = 0; jo < 4; ++jo) {
      const int kc = h * 2 + (jo >> 1);
      const int lgp = (jo & 1) * 2 + (lr >> 3);
      const int e = lr & 7;
#pragma unroll
      for (int v = 0; v < 4; ++v) {
        int n = q0 + lg * 4 + v;
        if (n < 197) {
          int m = b * 197 + n;
          Apk[((size_t)(kc * 788 + (m >> 4)) * 64 + (m & 15) + 16 * lgp) * 8 + e] = f2bf(oacc[jo][v]);
        }
      }
    }
  }
}

extern "C" void kernel_launch(void* const* d_in, const int* in_sizes, int n_in,
                              void* d_out, int out_size, void* d_ws, size_t ws_size,
                              hipStream_t stream) {
  const float* x      = (const float*)d_in[0];
  const float* qkv_w  = (const float*)d_in[1];
  const float* qkv_b  = (const float*)d_in[2];
  const float* qkv_la = (const float*)d_in[3];
  const float* qkv_lb = (const float*)d_in[4];
  const float* out_w  = (const float*)d_in[5];
  const float* out_b  = (const float*)d_in[6];
  const float* out_la = (const float*)d_in[7];
  const float* out_lb = (const float*)d_in[8];
  float* out = (float*)d_out;

  char* p = (char*)d_ws;
  auto carve = [&](size_t bytes) {
    char* r = p;
    p += (bytes + 255) & ~(size_t)255;
    return r;
  };
  unsigned short* Apk  = (unsigned short*)carve((size_t)788 * 24 * 512 * 2 + 32768);
  unsigned short* Wqpk = (unsigned short*)carve((size_t)144 * 24 * 512 * 2);
  unsigned short* Wopk = (unsigned short*)carve((size_t)48 * 24 * 512 * 2);
  unsigned short* Qpk  = (unsigned short*)carve((size_t)768 * 14336 * 2);
  unsigned short* Kpk  = (unsigned short*)carve((size_t)768 * 14336 * 2);
  unsigned short* Vtpk = (unsigned short*)carve((size_t)768 * 14336 * 2);

  // prep: 788 (pack x) + 864 (pack qkv_w + fold) + 288 (pack out_w + fold) + 192 (V pads)
  k_prep3<<<2132, 256, 0, stream>>>(x, qkv_w, out_w, qkv_la, qkv_lb, out_la, out_lb,
                                    Apk, Wqpk, Wopk, Vtpk);
  // qkv: 50 mg x 36 nt (block = 256x64)
  k_gp4<0, 36, 144><<<50 * 36, 256, 0, stream>>>(Apk, Wqpk, qkv_b, Qpk, Kpk, Vtpk, nullptr);
  k_attn8p<<<768, 512, 0, stream>>>(Qpk, Kpk, Vtpk, Apk);  // Apk now holds packed attn-out
  // out: 50 mg x 12 nt
  k_gp4<1, 12, 48><<<50 * 12, 256, 0, stream>>>(Apk, Wopk, out_b, nullptr, nullptr, nullptr, out);
}

// Round 14
// 152.919 us; speedup vs baseline: 1.7212x; 1.1379x over previous
//
#include <hip/hip_runtime.h>
#include <stdint.h>

typedef __attribute__((ext_vector_type(8))) short short8;
typedef __attribute__((ext_vector_type(4))) float f32x4;

#define SB __builtin_amdgcn_sched_barrier(0)

__device__ __forceinline__ unsigned short f2bf(float f) {
  unsigned u = __float_as_uint(f);
  u += 0x7FFF + ((u >> 16) & 1);
  return (unsigned short)(u >> 16);
}

// Packed fragment layout (k-major) for mfma_f32_16x16x32_bf16 operands:
// frag tile (rt, kc): short off = (kc*NRT + rt)*512 + L*8 + e,
// L = (row&15) + 16*((k&31)>>3), e = k&7. 1 frag = wave-contiguous 1KB.
// Per-head planes (28KB = 14336 shorts): Q/K: 14 rt (n) x 2 kc (d);
// Vt: 4 rt (d) x 7 kc (n), tile index kc*4+rt.

// ---------------- merged prep ----------------
__global__ __launch_bounds__(256) void k_prep3(const float* __restrict__ x,
                                               const float* __restrict__ qkv_w,
                                               const float* __restrict__ out_w,
                                               const float* __restrict__ qkv_la,
                                               const float* __restrict__ qkv_lb,
                                               const float* __restrict__ out_la,
                                               const float* __restrict__ out_lb,
                                               unsigned short* __restrict__ Apk,
                                               unsigned short* __restrict__ Wq,
                                               unsigned short* __restrict__ Wo,
                                               unsigned short* __restrict__ Vtpk) {
  __shared__ unsigned short xs[16 * 776];
  const int bid = blockIdx.x;
  const int t = threadIdx.x;
  if (bid < 788) {
    const int mt = bid;
    const float4* x4 = (const float4*)(x + (size_t)mt * 16 * 768);
#pragma unroll
    for (int i = 0; i < 12; ++i) {
      float4 v = x4[i * 256 + t];
      int e0 = (i * 256 + t) * 4;
      int row = e0 / 768, col = e0 - row * 768;
      unsigned short* d = &xs[row * 776 + col];
      d[0] = f2bf(v.x); d[1] = f2bf(v.y); d[2] = f2bf(v.z); d[3] = f2bf(v.w);
    }
    __syncthreads();
    const int w = t >> 6, l = t & 63;
    const int lr = l & 15, lg = l >> 4;
#pragma unroll
    for (int kk = 0; kk < 6; ++kk) {
      int kc = w * 6 + kk;
      short8 v = *(const short8*)(&xs[lr * 776 + kc * 32 + lg * 8]);
      *(short8*)(Apk + (size_t)(kc * 788 + mt) * 512 + l * 8) = v;
    }
  } else if (bid < 1940) {
    const bool isq = bid < 1652;
    const float* W = isq ? qkv_w : out_w;
    const float* la = isq ? qkv_la : out_la;
    const float* lb = isq ? qkv_lb : out_lb;
    unsigned short* dst = isq ? Wq : Wo;
    const int NRT = isq ? 144 : 48;
    const int base = isq ? 788 : 1652;
    int wv = ((bid - base) * 256 + t) >> 6;
    int l = t & 63;
    int rt = wv / 24, kc = wv - rt * 24;
    int lr = l & 15, lg = l >> 4;
    const int o = rt * 16 + lr;
    const int d0 = kc * 32 + lg * 8;
    const float* src = W + (size_t)o * 768 + d0;
    float4 a = *(const float4*)src;
    float4 b = *(const float4*)(src + 4);
    float wvv[8] = {a.x, a.y, a.z, a.w, b.x, b.y, b.z, b.w};
    const float4* lb4 = (const float4*)(lb + (size_t)o * 8);
    float4 p0 = lb4[0], p1 = lb4[1];
    float lbv[8] = {p0.x, p0.y, p0.z, p0.w, p1.x, p1.y, p1.z, p1.w};
#pragma unroll
    for (int r = 0; r < 8; ++r) {
      const float4* la4 = (const float4*)(la + (size_t)r * 768 + d0);
      float4 c = la4[0], dd = la4[1];
      float s = 2.0f * lbv[r];
      wvv[0] += s * c.x;  wvv[1] += s * c.y;  wvv[2] += s * c.z;  wvv[3] += s * c.w;
      wvv[4] += s * dd.x; wvv[5] += s * dd.y; wvv[6] += s * dd.z; wvv[7] += s * dd.w;
    }
    short8 oo;
#pragma unroll
    for (int e = 0; e < 8; ++e) oo[e] = f2bf(wvv[e]);
    *(short8*)(dst + (size_t)(kc * NRT + rt) * 512 + l * 8) = oo;
  } else {
    // zero V seq-pad in PACKED Vt layout: thread r = bh*64+hd, n in [197,224)
    int r = (bid - 1940) * 256 + t;  // [0, 49152)
    int bh = r >> 6, hd = r & 63;
    unsigned short* base = Vtpk + (size_t)bh * 14336 + (24 + (hd >> 4)) * 512;  // kc=6 plane
#pragma unroll
    for (int c = 0; c < 27; ++c) {
      int n = 197 + c;
      base[((hd & 15) + 16 * ((n & 31) >> 3)) * 8 + (n & 7)] = 0;
    }
  }
}

// ---------------- GEMM: B via LDS, A reg depth-2, shared-B 4-wave block ----------------
// MODE 0: qkv (NT=36, NRTB=144) scatter to PACKED Q/K/Vt + bias. MODE 1: out (NT=12, NRTB=48).
template <int MODE, int NT, int NRTB>
__global__ __launch_bounds__(256, 3) void k_gp4(
    const unsigned short* __restrict__ Apk, const unsigned short* __restrict__ Bpk,
    const float* __restrict__ bias, unsigned short* __restrict__ Qpk,
    unsigned short* __restrict__ Kpk, unsigned short* __restrict__ Vtpk,
    float* __restrict__ outp) {
  __shared__ __align__(16) char bl[49152];  // 12 kc-slots x 4 rt x 1KB
  const int w = threadIdx.x >> 6, l = threadIdx.x & 63;
  const int lr = l & 15, lg = l >> 4;
  const int nwg = gridDim.x;
  const int orig = blockIdx.x;
  const int qq = nwg >> 3, rr = nwg & 7, xcd = orig & 7;
  const int wgid = (xcd < rr ? xcd * (qq + 1) : rr * (qq + 1) + (xcd - rr) * qq) + (orig >> 3);
  const int mg = wgid / NT, nt = wgid - mg * NT;
  int mtw = mg * 4 + w;
  if (mtw > 196) mtw = 196;
  const int m0 = mtw * 64, n0 = nt * 64;

  const size_t KSA = 788 * 512;
  const unsigned short* pa = Apk + (size_t)(mtw * 4) * 512 + l * 8;

  auto* lds3 = (__attribute__((address_space(3))) char*)bl;
  auto STB = [&](int kc) {
    const unsigned short* g = Bpk + ((size_t)kc * NRTB + nt * 4 + w) * 512 + l * 8;
    __builtin_amdgcn_global_load_lds((const __attribute__((address_space(1))) void*)g,
                                     (__attribute__((address_space(3))) void*)(lds3 + ((kc % 12) * 4 + w) * 1024),
                                     16, 0, 0);
  };

  f32x4 acc[4][4];
#pragma unroll
  for (int i = 0; i < 4; ++i)
#pragma unroll
    for (int j = 0; j < 4; ++j) acc[i][j] = (f32x4){0.f, 0.f, 0.f, 0.f};

  short8 ab[2][4];
#define LDA4(dst, kt) \
  { const unsigned short* q_ = pa + (size_t)(kt) * KSA; \
    dst[0] = *(const short8*)(q_); dst[1] = *(const short8*)(q_ + 512); \
    dst[2] = *(const short8*)(q_ + 1024); dst[3] = *(const short8*)(q_ + 1536); }

#pragma unroll
  for (int kc = 0; kc < 12; ++kc) STB(kc);
  asm volatile("s_waitcnt vmcnt(0)" ::: "memory");
  SB;
  __builtin_amdgcn_s_barrier();
  LDA4(ab[0], 0);
  LDA4(ab[1], 1);

#pragma unroll
  for (int kt = 0; kt < 24; ++kt) {
    if (kt == 12) {
      asm volatile("s_waitcnt vmcnt(4)" ::: "memory");
      SB;
      __builtin_amdgcn_s_barrier();
    }
    short8 bfr[4];
    const char* sbase = (const char*)bl + (kt % 12) * 4096;
#pragma unroll
    for (int nf = 0; nf < 4; ++nf)
      bfr[nf] = *(const short8*)(sbase + nf * 1024 + l * 16);
    if (kt == 11) {
      asm volatile("s_waitcnt lgkmcnt(0)" ::: "memory");
      SB;
      __builtin_amdgcn_s_barrier();
#pragma unroll
      for (int kc = 12; kc < 24; ++kc) STB(kc);
    }
    __builtin_amdgcn_s_setprio(1);
#pragma unroll
    for (int mf = 0; mf < 4; ++mf)
#pragma unroll
      for (int nf = 0; nf < 4; ++nf)
        acc[mf][nf] = __builtin_amdgcn_mfma_f32_16x16x32_bf16(ab[kt & 1][mf], bfr[nf], acc[mf][nf], 0, 0, 0);
    __builtin_amdgcn_s_setprio(0);
    if (kt + 2 < 24) LDA4(ab[kt & 1], kt + 2);
  }
#undef LDA4

  // epilogue: bias; MODE 0 scatter into PACKED per-head fragment planes
  float bo[4];
#pragma unroll
  for (int nf = 0; nf < 4; ++nf) bo[nf] = bias[n0 + nf * 16 + lr];
  const int which = nt / 12;
  const int hh = nt - which * 12;
#pragma unroll
  for (int mf = 0; mf < 4; ++mf) {
#pragma unroll
    for (int v = 0; v < 4; ++v) {
      int m = m0 + mf * 16 + lg * 4 + v;
      int b = m / 197;
      int n = m - b * 197;
#pragma unroll
      for (int nf = 0; nf < 4; ++nf) {
        float val = acc[mf][nf][v] + bo[nf];
        if (MODE == 0) {
          int bh = b * 12 + hh;
          unsigned short hv = f2bf(val);
          if (which == 2) {
            Vtpk[(size_t)bh * 14336 + ((n >> 5) * 4 + nf) * 512 +
                 (lr + 16 * ((n & 31) >> 3)) * 8 + (n & 7)] = hv;
          } else {
            unsigned short* dst = (which == 0) ? Qpk : Kpk;
            dst[(size_t)bh * 14336 + ((nf >> 1) * 14 + (n >> 4)) * 512 +
                ((n & 15) + 16 * ((nf & 1) * 2 + (lr >> 3))) * 8 + (lr & 7)] = hv;
          }
        } else {
          outp[(size_t)m * 768 + n0 + nf * 16 + lr] = val;
        }
      }
    }
  }
}

// ---------------- attention: one WAVE per (bh, q-tile); 4 waves/block, high occupancy ----------------
// 9984 tasks = 2496 blocks x 4 waves. Per-wave P buffer 7KB (28KB/block -> 5 blocks/CU).
__global__ __launch_bounds__(256) void k_attn_w(const unsigned short* __restrict__ Qpk,
                                                const unsigned short* __restrict__ Kpk,
                                                const unsigned short* __restrict__ Vtpk,
                                                unsigned short* __restrict__ Apk) {
  __shared__ __align__(16) unsigned short Ps[4][7 * 512];
  const int w = threadIdx.x >> 6, l = threadIdx.x & 63;
  const int lr = l & 15, lg = l >> 4;
  // bijective XCD swizzle (nwg = 2496, divisible by 8)
  const int nwg = gridDim.x;
  const int orig = blockIdx.x;
  const int qq = nwg >> 3, xcd = orig & 7;
  const int wgid = xcd * qq + (orig >> 3);
  const int task = wgid * 4 + w;  // [0, 9984)
  const int bh = task / 13, t = task - bh * 13;
  const int b = bh / 12, h = bh - b * 12;
  const unsigned short* Qb = Qpk + (size_t)bh * 14336;
  const unsigned short* Kb = Kpk + (size_t)bh * 14336;
  const unsigned short* Vb = Vtpk + (size_t)bh * 14336;

  short8 aq0 = *(const short8*)(Qb + (size_t)t * 512 + l * 8);
  short8 aq1 = *(const short8*)(Qb + (size_t)(14 + t) * 512 + l * 8);
  f32x4 s[13];
#pragma unroll
  for (int jt = 0; jt < 13; ++jt) {  // jt=13 is all-pad: skipped, P=0
    f32x4 a = (f32x4){0.f, 0.f, 0.f, 0.f};
    short8 bk0 = *(const short8*)(Kb + (size_t)jt * 512 + l * 8);
    short8 bk1 = *(const short8*)(Kb + (size_t)(14 + jt) * 512 + l * 8);
    __builtin_amdgcn_s_setprio(1);
    a = __builtin_amdgcn_mfma_f32_16x16x32_bf16(aq0, bk0, a, 0, 0, 0);
    a = __builtin_amdgcn_mfma_f32_16x16x32_bf16(aq1, bk1, a, 0, 0, 0);
    __builtin_amdgcn_s_setprio(0);
    s[jt] = a;
  }
  // mask: only jt=12 has pad cols (k = 192+lr valid iff lr < 5)
#pragma unroll
  for (int v = 0; v < 4; ++v)
    if (lr >= 5) s[12][v] = -1.0e30f;
  float mx[4] = {-3.0e38f, -3.0e38f, -3.0e38f, -3.0e38f};
#pragma unroll
  for (int jt = 0; jt < 13; ++jt)
#pragma unroll
    for (int v = 0; v < 4; ++v) mx[v] = fmaxf(mx[v], s[jt][v]);
#pragma unroll
  for (int v = 0; v < 4; ++v) {
    mx[v] = fmaxf(mx[v], __shfl_xor(mx[v], 1));
    mx[v] = fmaxf(mx[v], __shfl_xor(mx[v], 2));
    mx[v] = fmaxf(mx[v], __shfl_xor(mx[v], 4));
    mx[v] = fmaxf(mx[v], __shfl_xor(mx[v], 8));
  }
  float sum[4] = {0.f, 0.f, 0.f, 0.f};
  const float cc = 0.125f * 1.44269504088896341f;
#pragma unroll
  for (int jt = 0; jt < 13; ++jt)
#pragma unroll
    for (int v = 0; v < 4; ++v) {
      float pv = exp2f((s[jt][v] - mx[v]) * cc);
      s[jt][v] = pv;
      sum[v] += pv;
    }
#pragma unroll
  for (int v = 0; v < 4; ++v) {
    sum[v] += __shfl_xor(sum[v], 1);
    sum[v] += __shfl_xor(sum[v], 2);
    sum[v] += __shfl_xor(sum[v], 4);
    sum[v] += __shfl_xor(sum[v], 8);
  }
  float inv[4];
#pragma unroll
  for (int v = 0; v < 4; ++v) inv[v] = 1.0f / sum[v];
  // write P in fragment-major layout (read side = contiguous b128)
  unsigned short* pw = &Ps[w][0];
#pragma unroll
  for (int jt = 0; jt < 13; ++jt) {
    const int base = (jt >> 1) * 512 + ((jt & 1) * 2 + (lr >> 3)) * 128 + (lr & 7);
#pragma unroll
    for (int v = 0; v < 4; ++v)
      pw[base + (lg * 4 + v) * 8] = f2bf(s[jt][v] * inv[v]);
  }
  {  // jt=13 pad tile: P = 0
    const int base = 6 * 512 + (2 + (lr >> 3)) * 128 + (lr & 7);
#pragma unroll
    for (int v = 0; v < 4; ++v) pw[base + (lg * 4 + v) * 8] = 0;
  }
  f32x4 oacc[4];
#pragma unroll
  for (int jo = 0; jo < 4; ++jo) oacc[jo] = (f32x4){0.f, 0.f, 0.f, 0.f};
#pragma unroll
  for (int kk = 0; kk < 7; ++kk) {
    short8 pa = *(const short8*)(pw + kk * 512 + l * 8);
    __builtin_amdgcn_s_setprio(1);
#pragma unroll
    for (int jo = 0; jo < 4; ++jo) {
      short8 bv = *(const short8*)(Vb + (size_t)(kk * 4 + jo) * 512 + l * 8);
      oacc[jo] = __builtin_amdgcn_mfma_f32_16x16x32_bf16(pa, bv, oacc[jo], 0, 0, 0);
    }
    __builtin_amdgcn_s_setprio(0);
  }
  // write PACKED k-major aout for the out-GEMM
  const int q0 = t * 16;
#pragma unroll
  for (int jo = 0; jo < 4; ++jo) {
    const int kc = h * 2 + (jo >> 1);
    const int lgp = (jo & 1) * 2 + (lr >> 3);
    const int e = lr & 7;
#pragma unroll
    for (int v = 0; v < 4; ++v) {
      int n = q0 + lg * 4 + v;
      if (n < 197) {
        int m = b * 197 + n;
        Apk[((size_t)(kc * 788 + (m >> 4)) * 64 + (m & 15) + 16 * lgp) * 8 + e] = f2bf(oacc[jo][v]);
      }
    }
  }
}

extern "C" void kernel_launch(void* const* d_in, const int* in_sizes, int n_in,
                              void* d_out, int out_size, void* d_ws, size_t ws_size,
                              hipStream_t stream) {
  const float* x      = (const float*)d_in[0];
  const float* qkv_w  = (const float*)d_in[1];
  const float* qkv_b  = (const float*)d_in[2];
  const float* qkv_la = (const float*)d_in[3];
  const float* qkv_lb = (const float*)d_in[4];
  const float* out_w  = (const float*)d_in[5];
  const float* out_b  = (const float*)d_in[6];
  const float* out_la = (const float*)d_in[7];
  const float* out_lb = (const float*)d_in[8];
  float* out = (float*)d_out;

  char* p = (char*)d_ws;
  auto carve = [&](size_t bytes) {
    char* r = p;
    p += (bytes + 255) & ~(size_t)255;
    return r;
  };
  unsigned short* Apk  = (unsigned short*)carve((size_t)788 * 24 * 512 * 2 + 32768);
  unsigned short* Wqpk = (unsigned short*)carve((size_t)144 * 24 * 512 * 2);
  unsigned short* Wopk = (unsigned short*)carve((size_t)48 * 24 * 512 * 2);
  unsigned short* Qpk  = (unsigned short*)carve((size_t)768 * 14336 * 2);
  unsigned short* Kpk  = (unsigned short*)carve((size_t)768 * 14336 * 2);
  unsigned short* Vtpk = (unsigned short*)carve((size_t)768 * 14336 * 2);

  // prep: 788 (pack x) + 864 (pack qkv_w + fold) + 288 (pack out_w + fold) + 192 (V pads)
  k_prep3<<<2132, 256, 0, stream>>>(x, qkv_w, out_w, qkv_la, qkv_lb, out_la, out_lb,
                                    Apk, Wqpk, Wopk, Vtpk);
  // qkv: 50 mg x 36 nt (block = 256x64)
  k_gp4<0, 36, 144><<<50 * 36, 256, 0, stream>>>(Apk, Wqpk, qkv_b, Qpk, Kpk, Vtpk, nullptr);
  // attention: 9984 wave-tasks = 2496 blocks x 4 waves
  k_attn_w<<<2496, 256, 0, stream>>>(Qpk, Kpk, Vtpk, Apk);  // Apk now holds packed attn-out
  // out: 50 mg x 12 nt
  k_gp4<1, 12, 48><<<50 * 12, 256, 0, stream>>>(Apk, Wopk, out_b, nullptr, nullptr, nullptr, out);
}